// Round 7
// baseline (662.836 us; speedup 1.0000x reference)
//
#include <hip/hip_runtime.h>
#include <math.h>

#define B_ 4
#define S_ 4096
#define D_ 1024
#define T_ 128
#define NC_ 32
#define DECAY_ 0.95f
#define NPAIR_ 528   // 32*33/2 chunk pairs per batch

typedef __bf16 bf16;
typedef __bf16 bf16x8 __attribute__((ext_vector_type(8)));
typedef __bf16 bf16x4 __attribute__((ext_vector_type(4)));
typedef float f32x4 __attribute__((ext_vector_type(4)));

__device__ __forceinline__ f32x4 mfma16(bf16x8 a, bf16x8 b, f32x4 c) {
  return __builtin_amdgcn_mfma_f32_16x16x32_bf16(a, b, c, 0, 0, 0);
}

// async global -> LDS, 16B per lane. lds base wave-uniform; HW writes
// base + lane*16, matching the linear As+tid*8 layout.
__device__ __forceinline__ void gload16(const bf16* g, bf16* l) {
  __builtin_amdgcn_global_load_lds(
      (const __attribute__((address_space(1))) unsigned int*)g,
      (__attribute__((address_space(3))) unsigned int*)l, 16, 0, 0);
}

// ---------------- fp32 -> bf16 casts ----------------
__global__ void cast_kernel(const float* __restrict__ src, bf16* __restrict__ dst, int n) {
  int i = (blockIdx.x * blockDim.x + threadIdx.x) * 4;
  int stride = gridDim.x * blockDim.x * 4;
  for (; i < n; i += stride) {
    float4 f = *(const float4*)(src + i);
    bf16x4 o = { (bf16)f.x, (bf16)f.y, (bf16)f.z, (bf16)f.w };
    *(bf16x4*)(dst + i) = o;
  }
}

// all 5 weight matrices in one launch: Wq|Wk|Wv|Wg -> Wcat, Wo -> Wo_bf
__global__ void wcast_kernel(const float* __restrict__ Wq, const float* __restrict__ Wk,
                             const float* __restrict__ Wv, const float* __restrict__ Wg,
                             const float* __restrict__ Wo,
                             bf16* __restrict__ Wcat, bf16* __restrict__ Wo_bf) {
  const int NW = 1 << 20;
  long gid = ((long)blockIdx.x * blockDim.x + threadIdx.x) * 4;  // [0, 5*NW)
  int sel = (int)(gid >> 20);
  int off = (int)(gid & (NW - 1));
  const float* src = (sel == 0) ? Wq : (sel == 1) ? Wk : (sel == 2) ? Wv
                   : (sel == 3) ? Wg : Wo;
  bf16* dst = (sel < 4) ? (Wcat + (long)sel * NW) : Wo_bf;
  float4 f = *(const float4*)(src + off);
  bf16x4 o = { (bf16)f.x, (bf16)f.y, (bf16)f.z, (bf16)f.w };
  *(bf16x4*)(dst + off) = o;
}

// ---------------- fused projection GEMM (2-phase prefetch) ----------------
// A[16384][1024] bf16, W[4096][1024] bf16 (y = x @ W.T)
// n0: [0,1K): q natural, [1K,2K): k natural, [2K,3K): v -> vT[b][c][e][t],
// [3K,4K): gate = sigmoid(.+bg) natural
__global__ __launch_bounds__(256) void gemm_proj(
    const bf16* __restrict__ A, const bf16* __restrict__ W,
    const float* __restrict__ bg,
    bf16* __restrict__ qo, bf16* __restrict__ ko,
    bf16* __restrict__ vT, bf16* __restrict__ go)
{
  __shared__ __align__(16) bf16 As[2][4096];
  __shared__ __align__(16) bf16 Bs[2][4096];
  const int K = 1024;
  int m0 = blockIdx.y * 128;
  int n0 = blockIdx.x * 128;
  int tid = threadIdx.x;
  int l = tid & 63;
  int w = tid >> 6;
  int wr = w >> 1, wc = w & 1;
  int wbase = w << 9;

  const bf16* Ab = A + (long)m0 * K;
  const bf16* Wb = W + (long)n0 * K;
  int lrow = tid >> 2, lcol = (tid & 3) * 8;

  f32x4 acc[4][4] = {};

  auto stage = [&](int buf, int k0) {
    gload16(Ab + (long)lrow * K + k0 + lcol, &As[buf][wbase]);
    gload16(Ab + (long)(lrow + 64) * K + k0 + lcol, &As[buf][2048 + wbase]);
    gload16(Wb + (long)lrow * K + k0 + lcol, &Bs[buf][wbase]);
    gload16(Wb + (long)(lrow + 64) * K + k0 + lcol, &Bs[buf][2048 + wbase]);
  };
  auto compute = [&](int buf) {
    bf16x8 af[4], bfr[4];
#pragma unroll
    for (int m = 0; m < 4; ++m)
      af[m] = *(const bf16x8*)(&As[buf][(wr * 64 + m * 16 + (l & 15)) * 32 + (l >> 4) * 8]);
#pragma unroll
    for (int n = 0; n < 4; ++n)
      bfr[n] = *(const bf16x8*)(&Bs[buf][(wc * 64 + n * 16 + (l & 15)) * 32 + (l >> 4) * 8]);
#pragma unroll
    for (int m = 0; m < 4; ++m)
#pragma unroll
      for (int n = 0; n < 4; ++n)
        acc[m][n] = mfma16(af[m], bfr[n], acc[m][n]);
  };

  stage(0, 0);
  __syncthreads();
  int cur = 0;
  for (int t = 0; t < 31; ++t) {
    stage(cur ^ 1, (t + 1) * 32);   // issue next tile BEFORE compute
    compute(cur);
    __syncthreads();                // drains vmcnt(0)+lgkmcnt(0): next buf ready
    cur ^= 1;
  }
  compute(cur);

  int widx = n0 >> 10;          // 0=q 1=k 2=v 3=g
  int b = m0 >> 12;
  int chunk = (m0 & 4095) >> 7;

#pragma unroll
  for (int m = 0; m < 4; ++m) {
    int row = wr * 64 + m * 16 + (l >> 4) * 4;
#pragma unroll
    for (int n = 0; n < 4; ++n) {
      int col = (n0 & 1023) + wc * 64 + n * 16 + (l & 15);
      if (widx == 2) {
        bf16x4 pk = { (bf16)acc[m][n][0], (bf16)acc[m][n][1],
                      (bf16)acc[m][n][2], (bf16)acc[m][n][3] };
        *(bf16x4*)(vT + ((long)(b * NC_ + chunk) * D_ + col) * T_ + row) = pk;
      } else if (widx < 2) {
        bf16* dst = (widx == 0) ? qo : ko;
#pragma unroll
        for (int r = 0; r < 4; ++r)
          dst[(long)(m0 + row + r) * D_ + col] = (bf16)acc[m][n][r];
      } else {
        float bgv = bg[col];
#pragma unroll
        for (int r = 0; r < 4; ++r) {
          float x = acc[m][n][r] + bgv;
          go[(long)(m0 + row + r) * D_ + col] = (bf16)(1.0f / (1.0f + __expf(-x)));
        }
      }
    }
  }
}

// ---------------- QK^T pass (2-phase prefetch) ----------------
// block = (pair p, batch b). P_nj[128 t][128 t'] = c_nj * q_n k_j^T, bf16.
__global__ __launch_bounds__(256) void qk_kernel(
    const bf16* __restrict__ q, const bf16* __restrict__ k,
    bf16* __restrict__ Plo, bf16* __restrict__ Phi)
{
  __shared__ __align__(16) bf16 As[2][4096];
  __shared__ __align__(16) bf16 Bs[2][4096];
  const int K = 1024;
  int p = blockIdx.x, b = blockIdx.y;
  int n = (int)((sqrtf(8.f * (float)p + 1.f) - 1.f) * 0.5f);
  while ((n + 1) * (n + 2) / 2 <= p) ++n;
  while (n * (n + 1) / 2 > p) --n;
  int j = p - n * (n + 1) / 2;

  int tid = threadIdx.x;
  int l = tid & 63, w = tid >> 6;
  int wr = w >> 1, wc = w & 1;
  int wbase = w << 9;

  const bf16* Ab = q + (long)(b * S_ + n * T_) * K;
  const bf16* Wb = k + (long)(b * S_ + j * T_) * K;
  int lrow = tid >> 2, lcol = (tid & 3) * 8;

  f32x4 acc[4][4] = {};

  auto stage = [&](int buf, int k0) {
    gload16(Ab + (long)lrow * K + k0 + lcol, &As[buf][wbase]);
    gload16(Ab + (long)(lrow + 64) * K + k0 + lcol, &As[buf][2048 + wbase]);
    gload16(Wb + (long)lrow * K + k0 + lcol, &Bs[buf][wbase]);
    gload16(Wb + (long)(lrow + 64) * K + k0 + lcol, &Bs[buf][2048 + wbase]);
  };
  auto compute = [&](int buf) {
    bf16x8 af[4], bfr[4];
#pragma unroll
    for (int m = 0; m < 4; ++m)
      af[m] = *(const bf16x8*)(&As[buf][(wr * 64 + m * 16 + (l & 15)) * 32 + (l >> 4) * 8]);
#pragma unroll
    for (int nn = 0; nn < 4; ++nn)
      bfr[nn] = *(const bf16x8*)(&Bs[buf][(wc * 64 + nn * 16 + (l & 15)) * 32 + (l >> 4) * 8]);
#pragma unroll
    for (int m = 0; m < 4; ++m)
#pragma unroll
      for (int nn = 0; nn < 4; ++nn)
        acc[m][nn] = mfma16(af[m], bfr[nn], acc[m][nn]);
  };

  stage(0, 0);
  __syncthreads();
  int cur = 0;
  for (int t = 0; t < 31; ++t) {
    stage(cur ^ 1, (t + 1) * 32);
    compute(cur);
    __syncthreads();
    cur ^= 1;
  }
  compute(cur);

  float c = powf(DECAY_, (float)(n - j)) * ((1.0f - DECAY_) / (float)T_);
  int tile = b * NPAIR_ + p;
  bf16* Pt = (tile < 1024) ? (Plo + (long)tile * 16384)
                           : (Phi + (long)(tile - 1024) * 16384);

#pragma unroll
  for (int m = 0; m < 4; ++m) {
    int row = wr * 64 + m * 16 + (l >> 4) * 4;
#pragma unroll
    for (int nn = 0; nn < 4; ++nn) {
      int col = wc * 64 + nn * 16 + (l & 15);
#pragma unroll
      for (int r = 0; r < 4; ++r)
        Pt[(long)(row + r) * T_ + col] = (bf16)(acc[m][nn][r] * c);
    }
  }
}

// ---------------- PV pass (2-phase prefetch over flattened (j,kk)) ----------------
// block = (e-tile, n desc, b). out[128 t][128 e] = sum_j P_nj v_j ; gate fused.
__global__ __launch_bounds__(256) void pv_kernel(
    const bf16* __restrict__ Plo, const bf16* __restrict__ Phi,
    const bf16* __restrict__ vT, const bf16* __restrict__ g,
    bf16* __restrict__ mid)
{
  __shared__ __align__(16) bf16 As[2][4096];
  __shared__ __align__(16) bf16 Bs[2][4096];
  int et = blockIdx.x;
  int n  = 31 - blockIdx.y;     // long blocks dispatch first
  int b  = blockIdx.z;
  int e0 = et * 128;
  int tid = threadIdx.x, l = tid & 63, w = tid >> 6;
  int wr = w >> 1, wc = w & 1;
  int wbase = w << 9;
  int lrow = tid >> 2, lcol = (tid & 3) * 8;
  int pbase = b * NPAIR_ + n * (n + 1) / 2;

  f32x4 acc[4][4] = {};

  auto stage = [&](int buf, int s) {
    int j = s >> 2, kk = s & 3;
    int tile = pbase + j;
    const bf16* Pa = ((tile < 1024) ? (Plo + (long)tile * 16384)
                                    : (Phi + (long)(tile - 1024) * 16384)) + kk * 32;
    const bf16* Va = vT + (long)(b * NC_ + j) * D_ * T_ + (long)e0 * T_ + kk * 32;
    gload16(Pa + (long)lrow * T_ + lcol, &As[buf][wbase]);
    gload16(Pa + (long)(lrow + 64) * T_ + lcol, &As[buf][2048 + wbase]);
    gload16(Va + (long)lrow * T_ + lcol, &Bs[buf][wbase]);
    gload16(Va + (long)(lrow + 64) * T_ + lcol, &Bs[buf][2048 + wbase]);
  };
  auto compute = [&](int buf) {
    bf16x8 af[4], bv[4];
#pragma unroll
    for (int m = 0; m < 4; ++m)
      af[m] = *(const bf16x8*)(&As[buf][(wr * 64 + m * 16 + (l & 15)) * 32 + (l >> 4) * 8]);
#pragma unroll
    for (int nn = 0; nn < 4; ++nn)
      bv[nn] = *(const bf16x8*)(&Bs[buf][(wc * 64 + nn * 16 + (l & 15)) * 32 + (l >> 4) * 8]);
#pragma unroll
    for (int m = 0; m < 4; ++m)
#pragma unroll
      for (int nn = 0; nn < 4; ++nn)
        acc[m][nn] = mfma16(af[m], bv[nn], acc[m][nn]);
  };

  int nsteps = (n + 1) * 4;
  stage(0, 0);
  __syncthreads();
  int cur = 0;
  for (int s = 0; s < nsteps - 1; ++s) {
    stage(cur ^ 1, s + 1);
    compute(cur);
    __syncthreads();
    cur ^= 1;
  }
  compute(cur);

#pragma unroll
  for (int m = 0; m < 4; ++m) {
    int trow = n * T_ + wr * 64 + m * 16 + (l >> 4) * 4;
#pragma unroll
    for (int nn = 0; nn < 4; ++nn) {
      int col = e0 + wc * 64 + nn * 16 + (l & 15);
#pragma unroll
      for (int r = 0; r < 4; ++r) {
        long idx = ((long)b * S_ + trow + r) * D_ + col;
        float gv = (float)g[idx];
        mid[idx] = (bf16)(acc[m][nn][r] * gv);
      }
    }
  }
}

// ---------------- output GEMM (2-phase prefetch, fp32 out) ----------------
__global__ __launch_bounds__(256) void gemm_out(
    const bf16* __restrict__ A, const bf16* __restrict__ W,
    float* __restrict__ C)
{
  __shared__ __align__(16) bf16 As[2][4096];
  __shared__ __align__(16) bf16 Bs[2][4096];
  const int K = 1024;
  int m0 = blockIdx.y * 128;
  int n0 = blockIdx.x * 128;
  int tid = threadIdx.x;
  int l = tid & 63, w = tid >> 6;
  int wr = w >> 1, wc = w & 1;
  int wbase = w << 9;

  const bf16* Ab = A + (long)m0 * K;
  const bf16* Wb = W + (long)n0 * K;
  int lrow = tid >> 2, lcol = (tid & 3) * 8;

  f32x4 acc[4][4] = {};

  auto stage = [&](int buf, int k0) {
    gload16(Ab + (long)lrow * K + k0 + lcol, &As[buf][wbase]);
    gload16(Ab + (long)(lrow + 64) * K + k0 + lcol, &As[buf][2048 + wbase]);
    gload16(Wb + (long)lrow * K + k0 + lcol, &Bs[buf][wbase]);
    gload16(Wb + (long)(lrow + 64) * K + k0 + lcol, &Bs[buf][2048 + wbase]);
  };
  auto compute = [&](int buf) {
    bf16x8 af[4], bfr[4];
#pragma unroll
    for (int m = 0; m < 4; ++m)
      af[m] = *(const bf16x8*)(&As[buf][(wr * 64 + m * 16 + (l & 15)) * 32 + (l >> 4) * 8]);
#pragma unroll
    for (int n = 0; n < 4; ++n)
      bfr[n] = *(const bf16x8*)(&Bs[buf][(wc * 64 + n * 16 + (l & 15)) * 32 + (l >> 4) * 8]);
#pragma unroll
    for (int m = 0; m < 4; ++m)
#pragma unroll
      for (int n = 0; n < 4; ++n)
        acc[m][n] = mfma16(af[m], bfr[n], acc[m][n]);
  };

  stage(0, 0);
  __syncthreads();
  int cur = 0;
  for (int t = 0; t < 31; ++t) {
    stage(cur ^ 1, (t + 1) * 32);
    compute(cur);
    __syncthreads();
    cur ^= 1;
  }
  compute(cur);

#pragma unroll
  for (int m = 0; m < 4; ++m) {
    int row = m0 + wr * 64 + m * 16 + (l >> 4) * 4;
#pragma unroll
    for (int n = 0; n < 4; ++n) {
      int col = n0 + wc * 64 + n * 16 + (l & 15);
#pragma unroll
      for (int r = 0; r < 4; ++r)
        C[(long)(row + r) * D_ + col] = acc[m][n][r];
    }
  }
}

// ---------------- launcher ----------------
extern "C" void kernel_launch(void* const* d_in, const int* in_sizes, int n_in,
                              void* d_out, int out_size, void* d_ws, size_t ws_size,
                              hipStream_t stream) {
  const float* h  = (const float*)d_in[0];
  const float* Wq = (const float*)d_in[2];
  const float* Wk = (const float*)d_in[3];
  const float* Wv = (const float*)d_in[4];
  const float* Wo = (const float*)d_in[5];
  const float* Wg = (const float*)d_in[6];
  const float* bg = (const float*)d_in[7];
  float* out = (float*)d_out;

  bf16* ws = (bf16*)d_ws;
  const long NHD = (long)B_ * S_ * D_;   // 16,777,216 (= exactly 1024 P tiles)
  const long NW  = (long)D_ * D_;

  bf16* h_bf  = ws;  ws += NHD;          // dead after proj -> reused as P_lo
  bf16* Wcat  = ws;  ws += 4 * NW;
  bf16* Wo_bf = ws;  ws += NW;
  bf16* q_bf  = ws;  ws += NHD;          // dead after qk -> reused as mid
  bf16* k_bf  = ws;  ws += NHD;
  bf16* vT    = ws;  ws += NHD;
  bf16* g_bf  = ws;  ws += NHD;
  bf16* P_hi  = ws;  ws += (long)(4 * NPAIR_ - 1024) * 16384;  // 1088 tiles

  bf16* P_lo = h_bf;
  bf16* mid  = q_bf;

  cast_kernel<<<4096, 256, 0, stream>>>(h, h_bf, (int)NHD);
  wcast_kernel<<<5120, 256, 0, stream>>>(Wq, Wk, Wv, Wg, Wo, Wcat, Wo_bf);

  gemm_proj<<<dim3(32, 128), 256, 0, stream>>>(h_bf, Wcat, bg, q_bf, k_bf, vT, g_bf);
  qk_kernel<<<dim3(NPAIR_, 4), 256, 0, stream>>>(q_bf, k_bf, P_lo, P_hi);
  pv_kernel<<<dim3(8, 32, 4), 256, 0, stream>>>(P_lo, P_hi, vT, g_bf, mid);
  gemm_out<<<dim3(8, 128), 256, 0, stream>>>(mid, Wo_bf, out);
}

// Round 9
// 659.407 us; speedup vs baseline: 1.0052x; 1.0052x over previous
//
#include <hip/hip_runtime.h>
#include <math.h>

#define B_ 4
#define S_ 4096
#define D_ 1024
#define T_ 128
#define NC_ 32
#define DECAY_ 0.95f
#define NPAIR_ 528   // 32*33/2 chunk pairs per batch

typedef __bf16 bf16;
typedef __bf16 bf16x8 __attribute__((ext_vector_type(8)));
typedef __bf16 bf16x4 __attribute__((ext_vector_type(4)));
typedef float f32x4 __attribute__((ext_vector_type(4)));

__device__ __forceinline__ f32x4 mfma16(bf16x8 a, bf16x8 b, f32x4 c) {
  return __builtin_amdgcn_mfma_f32_16x16x32_bf16(a, b, c, 0, 0, 0);
}

// async global -> LDS, 16B per lane. lds base wave-uniform; HW writes
// base + lane*16, matching the linear As+tid*8 layout.
__device__ __forceinline__ void gload16(const bf16* g, bf16* l) {
  __builtin_amdgcn_global_load_lds(
      (const __attribute__((address_space(1))) unsigned int*)g,
      (__attribute__((address_space(3))) unsigned int*)l, 16, 0, 0);
}

// ---------------- fp32 -> bf16 casts ----------------
__global__ void cast_kernel(const float* __restrict__ src, bf16* __restrict__ dst, int n) {
  int i = (blockIdx.x * blockDim.x + threadIdx.x) * 4;
  int stride = gridDim.x * blockDim.x * 4;
  for (; i < n; i += stride) {
    float4 f = *(const float4*)(src + i);
    bf16x4 o = { (bf16)f.x, (bf16)f.y, (bf16)f.z, (bf16)f.w };
    *(bf16x4*)(dst + i) = o;
  }
}

// all 5 weight matrices in one launch: Wq|Wk|Wv|Wg -> Wcat, Wo -> Wo_bf
__global__ void wcast_kernel(const float* __restrict__ Wq, const float* __restrict__ Wk,
                             const float* __restrict__ Wv, const float* __restrict__ Wg,
                             const float* __restrict__ Wo,
                             bf16* __restrict__ Wcat, bf16* __restrict__ Wo_bf) {
  const int NW = 1 << 20;
  long gid = ((long)blockIdx.x * blockDim.x + threadIdx.x) * 4;  // [0, 5*NW)
  int sel = (int)(gid >> 20);
  int off = (int)(gid & (NW - 1));
  const float* src = (sel == 0) ? Wq : (sel == 1) ? Wk : (sel == 2) ? Wv
                   : (sel == 3) ? Wg : Wo;
  bf16* dst = (sel < 4) ? (Wcat + (long)sel * NW) : Wo_bf;
  float4 f = *(const float4*)(src + off);
  bf16x4 o = { (bf16)f.x, (bf16)f.y, (bf16)f.z, (bf16)f.w };
  *(bf16x4*)(dst + off) = o;
}

// ---------------- fused projection GEMM (single-buffer, BK=64) ----------------
// A[16384][1024] bf16, W[4096][1024] bf16 (y = x @ W.T)
// n0: [0,1K): q natural, [1K,2K): k natural, [2K,3K): v -> vT[b][c][e][t],
// [3K,4K): gate = sigmoid(.+bg) natural
__global__ __launch_bounds__(256) void gemm_proj(
    const bf16* __restrict__ A, const bf16* __restrict__ W,
    const float* __restrict__ bg,
    bf16* __restrict__ qo, bf16* __restrict__ ko,
    bf16* __restrict__ vT, bf16* __restrict__ go)
{
  // [128 rows][64 cols] row-major; staged linearly: call c covers rows 32c..32c+31,
  // per-wave base = 2048c + 512w, lane writes 16B at +lane*8 elems.
  __shared__ __align__(16) bf16 As[128 * 64];
  __shared__ __align__(16) bf16 Bs[128 * 64];
  const int K = 1024;
  int m0 = blockIdx.y * 128;
  int n0 = blockIdx.x * 128;
  int tid = threadIdx.x;
  int l = tid & 63, w = tid >> 6;
  int wr = w >> 1, wc = w & 1;
  int wbase = w << 9;

  const bf16* Ab = A + (long)m0 * K;
  const bf16* Wb = W + (long)n0 * K;
  int srow = tid >> 3;            // 0..31 within each 32-row call group
  int scol = (tid & 7) * 8;       // 0..56

  f32x4 acc[4][4] = {};

  for (int k0 = 0; k0 < K; k0 += 64) {
#pragma unroll
    for (int c = 0; c < 4; ++c) {
      gload16(Ab + (long)(c * 32 + srow) * K + k0 + scol, As + c * 2048 + wbase);
      gload16(Wb + (long)(c * 32 + srow) * K + k0 + scol, Bs + c * 2048 + wbase);
    }
    __syncthreads();
#pragma unroll
    for (int ks = 0; ks < 2; ++ks) {
      bf16x8 af[4], bfr[4];
#pragma unroll
      for (int m = 0; m < 4; ++m)
        af[m] = *(const bf16x8*)(As + (wr * 64 + m * 16 + (l & 15)) * 64 + ks * 32 + (l >> 4) * 8);
#pragma unroll
      for (int n = 0; n < 4; ++n)
        bfr[n] = *(const bf16x8*)(Bs + (wc * 64 + n * 16 + (l & 15)) * 64 + ks * 32 + (l >> 4) * 8);
#pragma unroll
      for (int m = 0; m < 4; ++m)
#pragma unroll
        for (int n = 0; n < 4; ++n)
          acc[m][n] = mfma16(af[m], bfr[n], acc[m][n]);
    }
    __syncthreads();
  }

  int widx = n0 >> 10;          // 0=q 1=k 2=v 3=g
  int b = m0 >> 12;
  int chunk = (m0 & 4095) >> 7;

#pragma unroll
  for (int m = 0; m < 4; ++m) {
    int row = wr * 64 + m * 16 + (l >> 4) * 4;
#pragma unroll
    for (int n = 0; n < 4; ++n) {
      int col = (n0 & 1023) + wc * 64 + n * 16 + (l & 15);
      if (widx == 2) {
        bf16x4 pk = { (bf16)acc[m][n][0], (bf16)acc[m][n][1],
                      (bf16)acc[m][n][2], (bf16)acc[m][n][3] };
        *(bf16x4*)(vT + ((long)(b * NC_ + chunk) * D_ + col) * T_ + row) = pk;
      } else if (widx < 2) {
        bf16* dst = (widx == 0) ? qo : ko;
#pragma unroll
        for (int r = 0; r < 4; ++r)
          dst[(long)(m0 + row + r) * D_ + col] = (bf16)acc[m][n][r];
      } else {
        float bgv = bg[col];
#pragma unroll
        for (int r = 0; r < 4; ++r) {
          float x = acc[m][n][r] + bgv;
          go[(long)(m0 + row + r) * D_ + col] = (bf16)(1.0f / (1.0f + __expf(-x)));
        }
      }
    }
  }
}

// ---------------- QK^T pass (single-buffer, BK=32) ----------------
// block = (pair p, batch b). P_nj[128 t][128 t'] = c_nj * q_n k_j^T, bf16.
__global__ __launch_bounds__(256) void qk_kernel(
    const bf16* __restrict__ q, const bf16* __restrict__ k,
    bf16* __restrict__ Plo, bf16* __restrict__ Phi)
{
  __shared__ __align__(16) bf16 As[128 * 32];
  __shared__ __align__(16) bf16 Bs[128 * 32];
  const int K = 1024;
  int p = blockIdx.x, b = blockIdx.y;
  int n = (int)((sqrtf(8.f * (float)p + 1.f) - 1.f) * 0.5f);
  while ((n + 1) * (n + 2) / 2 <= p) ++n;
  while (n * (n + 1) / 2 > p) --n;
  int j = p - n * (n + 1) / 2;

  int tid = threadIdx.x;
  int l = tid & 63, w = tid >> 6;
  int wr = w >> 1, wc = w & 1;
  int wbase = w << 9;

  const bf16* Ab = q + (long)(b * S_ + n * T_) * K;
  const bf16* Wb = k + (long)(b * S_ + j * T_) * K;
  int lrow = tid >> 2, lcol = (tid & 3) * 8;

  f32x4 acc[4][4] = {};

  for (int k0 = 0; k0 < K; k0 += 32) {
    gload16(Ab + (long)lrow * K + k0 + lcol, As + wbase);
    gload16(Ab + (long)(lrow + 64) * K + k0 + lcol, As + 2048 + wbase);
    gload16(Wb + (long)lrow * K + k0 + lcol, Bs + wbase);
    gload16(Wb + (long)(lrow + 64) * K + k0 + lcol, Bs + 2048 + wbase);
    __syncthreads();
    bf16x8 af[4], bfr[4];
#pragma unroll
    for (int m = 0; m < 4; ++m)
      af[m] = *(const bf16x8*)(As + (wr * 64 + m * 16 + (l & 15)) * 32 + (l >> 4) * 8);
#pragma unroll
    for (int nn = 0; nn < 4; ++nn)
      bfr[nn] = *(const bf16x8*)(Bs + (wc * 64 + nn * 16 + (l & 15)) * 32 + (l >> 4) * 8);
#pragma unroll
    for (int m = 0; m < 4; ++m)
#pragma unroll
      for (int nn = 0; nn < 4; ++nn)
        acc[m][nn] = mfma16(af[m], bfr[nn], acc[m][nn]);
    __syncthreads();
  }

  float c = powf(DECAY_, (float)(n - j)) * ((1.0f - DECAY_) / (float)T_);
  int tile = b * NPAIR_ + p;
  bf16* Pt = (tile < 1024) ? (Plo + (long)tile * 16384)
                           : (Phi + (long)(tile - 1024) * 16384);

#pragma unroll
  for (int m = 0; m < 4; ++m) {
    int row = wr * 64 + m * 16 + (l >> 4) * 4;
#pragma unroll
    for (int nn = 0; nn < 4; ++nn) {
      int col = wc * 64 + nn * 16 + (l & 15);
#pragma unroll
      for (int r = 0; r < 4; ++r)
        Pt[(long)(row + r) * T_ + col] = (bf16)(acc[m][nn][r] * c);
    }
  }
}

// ---------------- PV pass (single-buffer, K=(n+1)*128) ----------------
// block = (e-tile, n desc, b). out[128 t][128 e] = sum_j P_nj v_j ; gate fused.
__global__ __launch_bounds__(256) void pv_kernel(
    const bf16* __restrict__ Plo, const bf16* __restrict__ Phi,
    const bf16* __restrict__ vT, const bf16* __restrict__ g,
    bf16* __restrict__ mid)
{
  __shared__ __align__(16) bf16 As[128 * 32];
  __shared__ __align__(16) bf16 Bs[128 * 32];
  int et = blockIdx.x;
  int n  = 31 - blockIdx.y;     // long blocks dispatch first
  int b  = blockIdx.z;
  int e0 = et * 128;
  int tid = threadIdx.x, l = tid & 63, w = tid >> 6;
  int wr = w >> 1, wc = w & 1;
  int wbase = w << 9;
  int lrow = tid >> 2, lcol = (tid & 3) * 8;
  int pbase = b * NPAIR_ + n * (n + 1) / 2;

  f32x4 acc[4][4] = {};

  for (int j = 0; j <= n; ++j) {
    int tile = pbase + j;
    const bf16* Pt = (tile < 1024) ? (Plo + (long)tile * 16384)
                                   : (Phi + (long)(tile - 1024) * 16384);
    const bf16* Vt = vT + (long)(b * NC_ + j) * D_ * T_ + (long)e0 * T_;
#pragma unroll
    for (int kk = 0; kk < 4; ++kk) {
      int k0 = kk * 32;
      gload16(Pt + (long)lrow * T_ + k0 + lcol, As + wbase);
      gload16(Pt + (long)(lrow + 64) * T_ + k0 + lcol, As + 2048 + wbase);
      gload16(Vt + (long)lrow * T_ + k0 + lcol, Bs + wbase);
      gload16(Vt + (long)(lrow + 64) * T_ + k0 + lcol, Bs + 2048 + wbase);
      __syncthreads();
      bf16x8 af[4], bv[4];
#pragma unroll
      for (int m = 0; m < 4; ++m)
        af[m] = *(const bf16x8*)(As + (wr * 64 + m * 16 + (l & 15)) * 32 + (l >> 4) * 8);
#pragma unroll
      for (int nn = 0; nn < 4; ++nn)
        bv[nn] = *(const bf16x8*)(Bs + (wc * 64 + nn * 16 + (l & 15)) * 32 + (l >> 4) * 8);
#pragma unroll
      for (int m = 0; m < 4; ++m)
#pragma unroll
        for (int nn = 0; nn < 4; ++nn)
          acc[m][nn] = mfma16(af[m], bv[nn], acc[m][nn]);
      __syncthreads();
    }
  }

#pragma unroll
  for (int m = 0; m < 4; ++m) {
    int trow = n * T_ + wr * 64 + m * 16 + (l >> 4) * 4;
#pragma unroll
    for (int nn = 0; nn < 4; ++nn) {
      int col = e0 + wc * 64 + nn * 16 + (l & 15);
#pragma unroll
      for (int r = 0; r < 4; ++r) {
        long idx = ((long)b * S_ + trow + r) * D_ + col;
        float gv = (float)g[idx];
        mid[idx] = (bf16)(acc[m][nn][r] * gv);
      }
    }
  }
}

// ---------------- output GEMM (single-buffer, fp32 out) ----------------
__global__ __launch_bounds__(256) void gemm_out(
    const bf16* __restrict__ A, const bf16* __restrict__ W,
    float* __restrict__ C)
{
  __shared__ __align__(16) bf16 As[128 * 32];
  __shared__ __align__(16) bf16 Bs[128 * 32];
  const int K = 1024;
  int m0 = blockIdx.y * 128;
  int n0 = blockIdx.x * 128;
  int tid = threadIdx.x;
  int l = tid & 63, w = tid >> 6;
  int wr = w >> 1, wc = w & 1;
  int wbase = w << 9;

  const bf16* Ab = A + (long)m0 * K;
  const bf16* Wb = W + (long)n0 * K;
  int lrow = tid >> 2, lcol = (tid & 3) * 8;

  f32x4 acc[4][4] = {};

  for (int k0 = 0; k0 < K; k0 += 32) {
    gload16(Ab + (long)lrow * K + k0 + lcol, As + wbase);
    gload16(Ab + (long)(lrow + 64) * K + k0 + lcol, As + 2048 + wbase);
    gload16(Wb + (long)lrow * K + k0 + lcol, Bs + wbase);
    gload16(Wb + (long)(lrow + 64) * K + k0 + lcol, Bs + 2048 + wbase);
    __syncthreads();
    bf16x8 af[4], bfr[4];
#pragma unroll
    for (int m = 0; m < 4; ++m)
      af[m] = *(const bf16x8*)(As + (wr * 64 + m * 16 + (l & 15)) * 32 + (l >> 4) * 8);
#pragma unroll
    for (int n = 0; n < 4; ++n)
      bfr[n] = *(const bf16x8*)(Bs + (wc * 64 + n * 16 + (l & 15)) * 32 + (l >> 4) * 8);
#pragma unroll
    for (int m = 0; m < 4; ++m)
#pragma unroll
      for (int n = 0; n < 4; ++n)
        acc[m][n] = mfma16(af[m], bfr[n], acc[m][n]);
    __syncthreads();
  }

#pragma unroll
  for (int m = 0; m < 4; ++m) {
    int row = m0 + wr * 64 + m * 16 + (l >> 4) * 4;
#pragma unroll
    for (int n = 0; n < 4; ++n) {
      int col = n0 + wc * 64 + n * 16 + (l & 15);
#pragma unroll
      for (int r = 0; r < 4; ++r)
        C[(long)(row + r) * D_ + col] = acc[m][n][r];
    }
  }
}

// ---------------- launcher ----------------
extern "C" void kernel_launch(void* const* d_in, const int* in_sizes, int n_in,
                              void* d_out, int out_size, void* d_ws, size_t ws_size,
                              hipStream_t stream) {
  const float* h  = (const float*)d_in[0];
  const float* Wq = (const float*)d_in[2];
  const float* Wk = (const float*)d_in[3];
  const float* Wv = (const float*)d_in[4];
  const float* Wo = (const float*)d_in[5];
  const float* Wg = (const float*)d_in[6];
  const float* bg = (const float*)d_in[7];
  float* out = (float*)d_out;

  bf16* ws = (bf16*)d_ws;
  const long NHD = (long)B_ * S_ * D_;   // 16,777,216 (= exactly 1024 P tiles)
  const long NW  = (long)D_ * D_;

  bf16* h_bf  = ws;  ws += NHD;          // dead after proj -> reused as P_lo
  bf16* Wcat  = ws;  ws += 4 * NW;
  bf16* Wo_bf = ws;  ws += NW;
  bf16* q_bf  = ws;  ws += NHD;          // dead after qk -> reused as mid
  bf16* k_bf  = ws;  ws += NHD;
  bf16* vT    = ws;  ws += NHD;
  bf16* g_bf  = ws;  ws += NHD;
  bf16* P_hi  = ws;  ws += (long)(4 * NPAIR_ - 1024) * 16384;  // 1088 tiles

  bf16* P_lo = h_bf;
  bf16* mid  = q_bf;

  cast_kernel<<<4096, 256, 0, stream>>>(h, h_bf, (int)NHD);
  wcast_kernel<<<5120, 256, 0, stream>>>(Wq, Wk, Wv, Wg, Wo, Wcat, Wo_bf);

  gemm_proj<<<dim3(32, 128), 256, 0, stream>>>(h_bf, Wcat, bg, q_bf, k_bf, vT, g_bf);
  qk_kernel<<<dim3(NPAIR_, 4), 256, 0, stream>>>(q_bf, k_bf, P_lo, P_hi);
  pv_kernel<<<dim3(8, 32, 4), 256, 0, stream>>>(P_lo, P_hi, vT, g_bf, mid);
  gemm_out<<<dim3(8, 128), 256, 0, stream>>>(mid, Wo_bf, out);
}

// Round 10
// 599.202 us; speedup vs baseline: 1.1062x; 1.1005x over previous
//
#include <hip/hip_runtime.h>
#include <math.h>

#define B_ 4
#define S_ 4096
#define D_ 1024
#define T_ 128
#define NC_ 32
#define DECAY_ 0.95f
#define NPAIR_ 528   // 32*33/2 chunk pairs per batch

typedef __bf16 bf16;
typedef __bf16 bf16x8 __attribute__((ext_vector_type(8)));
typedef __bf16 bf16x4 __attribute__((ext_vector_type(4)));
typedef float f32x4 __attribute__((ext_vector_type(4)));

__device__ __forceinline__ f32x4 mfma16(bf16x8 a, bf16x8 b, f32x4 c) {
  return __builtin_amdgcn_mfma_f32_16x16x32_bf16(a, b, c, 0, 0, 0);
}

// async global -> LDS, 16B per lane. lds base wave-uniform; HW writes base+lane*16.
__device__ __forceinline__ void gload16(const bf16* g, bf16* l) {
  __builtin_amdgcn_global_load_lds(
      (const __attribute__((address_space(1))) unsigned int*)g,
      (__attribute__((address_space(3))) unsigned int*)l, 16, 0, 0);
}

// ---------------- fp32 -> bf16 casts ----------------
__global__ void cast_kernel(const float* __restrict__ src, bf16* __restrict__ dst, int n) {
  int i = (blockIdx.x * blockDim.x + threadIdx.x) * 4;
  int stride = gridDim.x * blockDim.x * 4;
  for (; i < n; i += stride) {
    float4 f = *(const float4*)(src + i);
    bf16x4 o = { (bf16)f.x, (bf16)f.y, (bf16)f.z, (bf16)f.w };
    *(bf16x4*)(dst + i) = o;
  }
}

__global__ void wcast_kernel(const float* __restrict__ Wq, const float* __restrict__ Wk,
                             const float* __restrict__ Wv, const float* __restrict__ Wg,
                             const float* __restrict__ Wo,
                             bf16* __restrict__ Wcat, bf16* __restrict__ Wo_bf) {
  const int NW = 1 << 20;
  long gid = ((long)blockIdx.x * blockDim.x + threadIdx.x) * 4;  // [0, 5*NW)
  int sel = (int)(gid >> 20);
  int off = (int)(gid & (NW - 1));
  const float* src = (sel == 0) ? Wq : (sel == 1) ? Wk : (sel == 2) ? Wv
                   : (sel == 3) ? Wg : Wo;
  bf16* dst = (sel < 4) ? (Wcat + (long)sel * NW) : Wo_bf;
  float4 f = *(const float4*)(src + off);
  bf16x4 o = { (bf16)f.x, (bf16)f.y, (bf16)f.z, (bf16)f.w };
  *(bf16x4*)(dst + off) = o;
}

// ---------------- fused projection GEMM: 256x256, BK=64, counted-vmcnt depth-2 ----
// 512 threads, 8 waves (2 Mx4 N). LDS swizzle: segment (r, s=col/8) stored at slot
// r*8 + (s^(r&7)). Write: linear dest + pre-swizzled GLOBAL source col. Read: same XOR.
// A[16384][1024], W[4096][1024] (y = x @ W.T). n0 block spans one weight (256|1024).
__global__ __launch_bounds__(512, 1) void gemm_proj(
    const bf16* __restrict__ A, const bf16* __restrict__ W,
    const float* __restrict__ bg,
    bf16* __restrict__ qo, bf16* __restrict__ ko,
    bf16* __restrict__ vT, bf16* __restrict__ go)
{
  __shared__ __align__(16) bf16 As[2][256 * 64];   // 64 KB
  __shared__ __align__(16) bf16 Bs[2][256 * 64];   // 64 KB
  const int K = 1024;
  const int NT = 16;                                // K / 64
  int m0 = blockIdx.y * 256;
  int n0 = blockIdx.x * 256;
  int t = threadIdx.x;
  int l = t & 63, w = t >> 6;
  int wr = w >> 2, wc = w & 3;                      // 2x4 wave grid; wave tile 128x64

  const bf16* Ab = A + (long)m0 * K;
  const bf16* Wb = W + (long)n0 * K;

  int srow_off = t >> 3;                            // 0..63 within each 64-row call group
  int scol_swz = (((t & 7) ^ ((t >> 3) & 7)) * 8);  // pre-swizzled source col
  int wdst = w << 9;                                // wave-uniform LDS base (elems)

  f32x4 acc[8][4] = {};

  auto stage = [&](int buf, int kt) {
#pragma unroll
    for (int c = 0; c < 4; ++c) {
      int r = c * 64 + srow_off;
      gload16(Ab + (long)r * K + kt * 64 + scol_swz, &As[buf][c * 4096 + wdst]);
      gload16(Wb + (long)r * K + kt * 64 + scol_swz, &Bs[buf][c * 4096 + wdst]);
    }
  };

  auto compute = [&](int buf) {
    bf16x8 bfrag[4][2];
#pragma unroll
    for (int fn = 0; fn < 4; ++fn)
#pragma unroll
      for (int ks = 0; ks < 2; ++ks) {
        int rb = wc * 64 + fn * 16 + (l & 15);
        int sb = ks * 4 + (l >> 4);
        bfrag[fn][ks] = *(const bf16x8*)(&Bs[buf][rb * 64 + ((sb ^ (rb & 7)) * 8)]);
      }
#pragma unroll
    for (int fm = 0; fm < 8; ++fm) {
      int ra = wr * 128 + fm * 16 + (l & 15);
      int s0 = (l >> 4);
      bf16x8 a0 = *(const bf16x8*)(&As[buf][ra * 64 + ((s0 ^ (ra & 7)) * 8)]);
      bf16x8 a1 = *(const bf16x8*)(&As[buf][ra * 64 + (((s0 + 4) ^ (ra & 7)) * 8)]);
#pragma unroll
      for (int fn = 0; fn < 4; ++fn) {
        acc[fm][fn] = mfma16(a0, bfrag[fn][0], acc[fm][fn]);
        acc[fm][fn] = mfma16(a1, bfrag[fn][1], acc[fm][fn]);
      }
    }
  };

  stage(0, 0);
  stage(1, 1);
  for (int kt = 0; kt < NT; ++kt) {
    if (kt < NT - 1) {
      asm volatile("s_waitcnt vmcnt(8)" ::: "memory");   // own kt loads done; kt+1's stay in flight
    } else {
      asm volatile("s_waitcnt vmcnt(0)" ::: "memory");
    }
    __builtin_amdgcn_s_barrier();                        // all waves' kt loads done
    __builtin_amdgcn_sched_barrier(0);
    compute(kt & 1);
    __builtin_amdgcn_s_barrier();                        // all waves done reading buf
    if (kt + 2 < NT) stage(kt & 1, kt + 2);
  }

  int widx = n0 >> 10;          // 0=q 1=k 2=v 3=g (256 | 1024, so uniform per block)
  int b = m0 >> 12;             // 256 | 4096, so uniform per block

#pragma unroll
  for (int fm = 0; fm < 8; ++fm) {
    int rowg = m0 + wr * 128 + fm * 16 + (l >> 4) * 4;
#pragma unroll
    for (int fn = 0; fn < 4; ++fn) {
      int col = (n0 & 1023) + wc * 64 + fn * 16 + (l & 15);
      if (widx == 2) {
        int chunk = (rowg & 4095) >> 7;
        int trow = rowg & 127;
        bf16x4 pk = { (bf16)acc[fm][fn][0], (bf16)acc[fm][fn][1],
                      (bf16)acc[fm][fn][2], (bf16)acc[fm][fn][3] };
        *(bf16x4*)(vT + ((long)(b * NC_ + chunk) * D_ + col) * T_ + trow) = pk;
      } else if (widx < 2) {
        bf16* dst = (widx == 0) ? qo : ko;
#pragma unroll
        for (int r = 0; r < 4; ++r)
          dst[(long)(rowg + r) * D_ + col] = (bf16)acc[fm][fn][r];
      } else {
        float bgv = bg[col];
#pragma unroll
        for (int r = 0; r < 4; ++r) {
          float x = acc[fm][fn][r] + bgv;
          go[(long)(rowg + r) * D_ + col] = (bf16)(1.0f / (1.0f + __expf(-x)));
        }
      }
    }
  }
}

// ---------------- QK^T pass (round-5 form: single-buffer, BK=32) ----------------
__global__ __launch_bounds__(256) void qk_kernel(
    const bf16* __restrict__ q, const bf16* __restrict__ k,
    bf16* __restrict__ Plo, bf16* __restrict__ Phi)
{
  __shared__ __align__(16) bf16 As[128 * 32];
  __shared__ __align__(16) bf16 Bs[128 * 32];
  const int K = 1024;
  int p = blockIdx.x, b = blockIdx.y;
  int n = (int)((sqrtf(8.f * (float)p + 1.f) - 1.f) * 0.5f);
  while ((n + 1) * (n + 2) / 2 <= p) ++n;
  while (n * (n + 1) / 2 > p) --n;
  int j = p - n * (n + 1) / 2;

  int tid = threadIdx.x;
  int l = tid & 63, w = tid >> 6;
  int wr = w >> 1, wc = w & 1;
  int wbase = w << 9;

  const bf16* Ab = q + (long)(b * S_ + n * T_) * K;
  const bf16* Wb = k + (long)(b * S_ + j * T_) * K;
  int lrow = tid >> 2, lcol = (tid & 3) * 8;

  f32x4 acc[4][4] = {};

  for (int k0 = 0; k0 < K; k0 += 32) {
    gload16(Ab + (long)lrow * K + k0 + lcol, As + wbase);
    gload16(Ab + (long)(lrow + 64) * K + k0 + lcol, As + 2048 + wbase);
    gload16(Wb + (long)lrow * K + k0 + lcol, Bs + wbase);
    gload16(Wb + (long)(lrow + 64) * K + k0 + lcol, Bs + 2048 + wbase);
    __syncthreads();
    bf16x8 af[4], bfr[4];
#pragma unroll
    for (int m = 0; m < 4; ++m)
      af[m] = *(const bf16x8*)(As + (wr * 64 + m * 16 + (l & 15)) * 32 + (l >> 4) * 8);
#pragma unroll
    for (int nn = 0; nn < 4; ++nn)
      bfr[nn] = *(const bf16x8*)(Bs + (wc * 64 + nn * 16 + (l & 15)) * 32 + (l >> 4) * 8);
#pragma unroll
    for (int m = 0; m < 4; ++m)
#pragma unroll
      for (int nn = 0; nn < 4; ++nn)
        acc[m][nn] = mfma16(af[m], bfr[nn], acc[m][nn]);
    __syncthreads();
  }

  float c = powf(DECAY_, (float)(n - j)) * ((1.0f - DECAY_) / (float)T_);
  int tile = b * NPAIR_ + p;
  bf16* Pt = (tile < 1024) ? (Plo + (long)tile * 16384)
                           : (Phi + (long)(tile - 1024) * 16384);

#pragma unroll
  for (int m = 0; m < 4; ++m) {
    int row = wr * 64 + m * 16 + (l >> 4) * 4;
#pragma unroll
    for (int nn = 0; nn < 4; ++nn) {
      int col = wc * 64 + nn * 16 + (l & 15);
#pragma unroll
      for (int r = 0; r < 4; ++r)
        Pt[(long)(row + r) * T_ + col] = (bf16)(acc[m][nn][r] * c);
    }
  }
}

// ---------------- PV pass (round-5 form) ----------------
__global__ __launch_bounds__(256) void pv_kernel(
    const bf16* __restrict__ Plo, const bf16* __restrict__ Phi,
    const bf16* __restrict__ vT, const bf16* __restrict__ g,
    bf16* __restrict__ mid)
{
  __shared__ __align__(16) bf16 As[128 * 32];
  __shared__ __align__(16) bf16 Bs[128 * 32];
  int et = blockIdx.x;
  int n  = 31 - blockIdx.y;     // long blocks dispatch first
  int b  = blockIdx.z;
  int e0 = et * 128;
  int tid = threadIdx.x, l = tid & 63, w = tid >> 6;
  int wr = w >> 1, wc = w & 1;
  int wbase = w << 9;
  int lrow = tid >> 2, lcol = (tid & 3) * 8;
  int pbase = b * NPAIR_ + n * (n + 1) / 2;

  f32x4 acc[4][4] = {};

  for (int j = 0; j <= n; ++j) {
    int tile = pbase + j;
    const bf16* Pt = (tile < 1024) ? (Plo + (long)tile * 16384)
                                   : (Phi + (long)(tile - 1024) * 16384);
    const bf16* Vt = vT + (long)(b * NC_ + j) * D_ * T_ + (long)e0 * T_;
#pragma unroll
    for (int kk = 0; kk < 4; ++kk) {
      int k0 = kk * 32;
      gload16(Pt + (long)lrow * T_ + k0 + lcol, As + wbase);
      gload16(Pt + (long)(lrow + 64) * T_ + k0 + lcol, As + 2048 + wbase);
      gload16(Vt + (long)lrow * T_ + k0 + lcol, Bs + wbase);
      gload16(Vt + (long)(lrow + 64) * T_ + k0 + lcol, Bs + 2048 + wbase);
      __syncthreads();
      bf16x8 af[4], bv[4];
#pragma unroll
      for (int m = 0; m < 4; ++m)
        af[m] = *(const bf16x8*)(As + (wr * 64 + m * 16 + (l & 15)) * 32 + (l >> 4) * 8);
#pragma unroll
      for (int nn = 0; nn < 4; ++nn)
        bv[nn] = *(const bf16x8*)(Bs + (wc * 64 + nn * 16 + (l & 15)) * 32 + (l >> 4) * 8);
#pragma unroll
      for (int m = 0; m < 4; ++m)
#pragma unroll
        for (int nn = 0; nn < 4; ++nn)
          acc[m][nn] = mfma16(af[m], bv[nn], acc[m][nn]);
      __syncthreads();
    }
  }

#pragma unroll
  for (int m = 0; m < 4; ++m) {
    int trow = n * T_ + wr * 64 + m * 16 + (l >> 4) * 4;
#pragma unroll
    for (int nn = 0; nn < 4; ++nn) {
      int col = e0 + wc * 64 + nn * 16 + (l & 15);
#pragma unroll
      for (int r = 0; r < 4; ++r) {
        long idx = ((long)b * S_ + trow + r) * D_ + col;
        float gv = (float)g[idx];
        mid[idx] = (bf16)(acc[m][nn][r] * gv);
      }
    }
  }
}

// ---------------- output GEMM (round-5 form, fp32 out) ----------------
__global__ __launch_bounds__(256) void gemm_out(
    const bf16* __restrict__ A, const bf16* __restrict__ W,
    float* __restrict__ C)
{
  __shared__ __align__(16) bf16 As[128 * 32];
  __shared__ __align__(16) bf16 Bs[128 * 32];
  const int K = 1024;
  int m0 = blockIdx.y * 128;
  int n0 = blockIdx.x * 128;
  int tid = threadIdx.x;
  int l = tid & 63, w = tid >> 6;
  int wr = w >> 1, wc = w & 1;
  int wbase = w << 9;

  const bf16* Ab = A + (long)m0 * K;
  const bf16* Wb = W + (long)n0 * K;
  int lrow = tid >> 2, lcol = (tid & 3) * 8;

  f32x4 acc[4][4] = {};

  for (int k0 = 0; k0 < K; k0 += 32) {
    gload16(Ab + (long)lrow * K + k0 + lcol, As + wbase);
    gload16(Ab + (long)(lrow + 64) * K + k0 + lcol, As + 2048 + wbase);
    gload16(Wb + (long)lrow * K + k0 + lcol, Bs + wbase);
    gload16(Wb + (long)(lrow + 64) * K + k0 + lcol, Bs + 2048 + wbase);
    __syncthreads();
    bf16x8 af[4], bfr[4];
#pragma unroll
    for (int m = 0; m < 4; ++m)
      af[m] = *(const bf16x8*)(As + (wr * 64 + m * 16 + (l & 15)) * 32 + (l >> 4) * 8);
#pragma unroll
    for (int n = 0; n < 4; ++n)
      bfr[n] = *(const bf16x8*)(Bs + (wc * 64 + n * 16 + (l & 15)) * 32 + (l >> 4) * 8);
#pragma unroll
    for (int m = 0; m < 4; ++m)
#pragma unroll
      for (int n = 0; n < 4; ++n)
        acc[m][n] = mfma16(af[m], bfr[n], acc[m][n]);
    __syncthreads();
  }

#pragma unroll
  for (int m = 0; m < 4; ++m) {
    int row = m0 + wr * 64 + m * 16 + (l >> 4) * 4;
#pragma unroll
    for (int n = 0; n < 4; ++n) {
      int col = n0 + wc * 64 + n * 16 + (l & 15);
#pragma unroll
      for (int r = 0; r < 4; ++r)
        C[(long)(row + r) * D_ + col] = acc[m][n][r];
    }
  }
}

// ---------------- launcher ----------------
extern "C" void kernel_launch(void* const* d_in, const int* in_sizes, int n_in,
                              void* d_out, int out_size, void* d_ws, size_t ws_size,
                              hipStream_t stream) {
  const float* h  = (const float*)d_in[0];
  const float* Wq = (const float*)d_in[2];
  const float* Wk = (const float*)d_in[3];
  const float* Wv = (const float*)d_in[4];
  const float* Wo = (const float*)d_in[5];
  const float* Wg = (const float*)d_in[6];
  const float* bg = (const float*)d_in[7];
  float* out = (float*)d_out;

  bf16* ws = (bf16*)d_ws;
  const long NHD = (long)B_ * S_ * D_;   // 16,777,216 (= exactly 1024 P tiles)
  const long NW  = (long)D_ * D_;

  bf16* h_bf  = ws;  ws += NHD;          // dead after proj -> reused as P_lo
  bf16* Wcat  = ws;  ws += 4 * NW;
  bf16* Wo_bf = ws;  ws += NW;
  bf16* q_bf  = ws;  ws += NHD;          // dead after qk -> reused as mid
  bf16* k_bf  = ws;  ws += NHD;
  bf16* vT    = ws;  ws += NHD;
  bf16* g_bf  = ws;  ws += NHD;
  bf16* P_hi  = ws;  ws += (long)(4 * NPAIR_ - 1024) * 16384;  // 1088 tiles

  bf16* P_lo = h_bf;
  bf16* mid  = q_bf;

  cast_kernel<<<4096, 256, 0, stream>>>(h, h_bf, (int)NHD);
  wcast_kernel<<<5120, 256, 0, stream>>>(Wq, Wk, Wv, Wg, Wo, Wcat, Wo_bf);

  gemm_proj<<<dim3(16, 64), 512, 0, stream>>>(h_bf, Wcat, bg, q_bf, k_bf, vT, g_bf);
  qk_kernel<<<dim3(NPAIR_, 4), 256, 0, stream>>>(q_bf, k_bf, P_lo, P_hi);
  pv_kernel<<<dim3(8, 32, 4), 256, 0, stream>>>(P_lo, P_hi, vT, g_bf, mid);
  gemm_out<<<dim3(8, 128), 256, 0, stream>>>(mid, Wo_bf, out);
}

// Round 11
// 574.140 us; speedup vs baseline: 1.1545x; 1.0437x over previous
//
#include <hip/hip_runtime.h>
#include <math.h>

#define B_ 4
#define S_ 4096
#define D_ 1024
#define T_ 128
#define NC_ 32
#define DECAY_ 0.95f
#define NPAIR_ 528   // 32*33/2 chunk pairs per batch

typedef __bf16 bf16;
typedef __bf16 bf16x8 __attribute__((ext_vector_type(8)));
typedef __bf16 bf16x4 __attribute__((ext_vector_type(4)));
typedef float f32x4 __attribute__((ext_vector_type(4)));

__device__ __forceinline__ f32x4 mfma16(bf16x8 a, bf16x8 b, f32x4 c) {
  return __builtin_amdgcn_mfma_f32_16x16x32_bf16(a, b, c, 0, 0, 0);
}

// async global -> LDS, 16B per lane. lds base wave-uniform; HW writes base+lane*16.
__device__ __forceinline__ void gload16(const bf16* g, bf16* l) {
  __builtin_amdgcn_global_load_lds(
      (const __attribute__((address_space(1))) unsigned int*)g,
      (__attribute__((address_space(3))) unsigned int*)l, 16, 0, 0);
}

// ---------------- fp32 -> bf16 casts ----------------
__global__ void cast_kernel(const float* __restrict__ src, bf16* __restrict__ dst, int n) {
  int i = (blockIdx.x * blockDim.x + threadIdx.x) * 4;
  int stride = gridDim.x * blockDim.x * 4;
  for (; i < n; i += stride) {
    float4 f = *(const float4*)(src + i);
    bf16x4 o = { (bf16)f.x, (bf16)f.y, (bf16)f.z, (bf16)f.w };
    *(bf16x4*)(dst + i) = o;
  }
}

__global__ void wcast_kernel(const float* __restrict__ Wq, const float* __restrict__ Wk,
                             const float* __restrict__ Wv, const float* __restrict__ Wg,
                             const float* __restrict__ Wo,
                             bf16* __restrict__ Wcat, bf16* __restrict__ Wo_bf) {
  const int NW = 1 << 20;
  long gid = ((long)blockIdx.x * blockDim.x + threadIdx.x) * 4;  // [0, 5*NW)
  int sel = (int)(gid >> 20);
  int off = (int)(gid & (NW - 1));
  const float* src = (sel == 0) ? Wq : (sel == 1) ? Wk : (sel == 2) ? Wv
                   : (sel == 3) ? Wg : Wo;
  bf16* dst = (sel < 4) ? (Wcat + (long)sel * NW) : Wo_bf;
  float4 f = *(const float4*)(src + off);
  bf16x4 o = { (bf16)f.x, (bf16)f.y, (bf16)f.z, (bf16)f.w };
  *(bf16x4*)(dst + off) = o;
}

// ---------------- fused projection GEMM: 256x256, BK=64, counted-vmcnt depth-2 ----
// (unchanged from round 10: 183 us, 0 bank conflicts)
__global__ __launch_bounds__(512, 1) void gemm_proj(
    const bf16* __restrict__ A, const bf16* __restrict__ W,
    const float* __restrict__ bg,
    bf16* __restrict__ qo, bf16* __restrict__ ko,
    bf16* __restrict__ vT, bf16* __restrict__ go)
{
  __shared__ __align__(16) bf16 As[2][256 * 64];   // 64 KB
  __shared__ __align__(16) bf16 Bs[2][256 * 64];   // 64 KB
  const int K = 1024;
  const int NT = 16;                                // K / 64
  int m0 = blockIdx.y * 256;
  int n0 = blockIdx.x * 256;
  int t = threadIdx.x;
  int l = t & 63, w = t >> 6;
  int wr = w >> 2, wc = w & 3;                      // 2x4 wave grid; wave tile 128x64

  const bf16* Ab = A + (long)m0 * K;
  const bf16* Wb = W + (long)n0 * K;

  int srow_off = t >> 3;
  int scol_swz = (((t & 7) ^ ((t >> 3) & 7)) * 8);
  int wdst = w << 9;

  f32x4 acc[8][4] = {};

  auto stage = [&](int buf, int kt) {
#pragma unroll
    for (int c = 0; c < 4; ++c) {
      int r = c * 64 + srow_off;
      gload16(Ab + (long)r * K + kt * 64 + scol_swz, &As[buf][c * 4096 + wdst]);
      gload16(Wb + (long)r * K + kt * 64 + scol_swz, &Bs[buf][c * 4096 + wdst]);
    }
  };

  auto compute = [&](int buf) {
    bf16x8 bfrag[4][2];
#pragma unroll
    for (int fn = 0; fn < 4; ++fn)
#pragma unroll
      for (int ks = 0; ks < 2; ++ks) {
        int rb = wc * 64 + fn * 16 + (l & 15);
        int sb = ks * 4 + (l >> 4);
        bfrag[fn][ks] = *(const bf16x8*)(&Bs[buf][rb * 64 + ((sb ^ (rb & 7)) * 8)]);
      }
#pragma unroll
    for (int fm = 0; fm < 8; ++fm) {
      int ra = wr * 128 + fm * 16 + (l & 15);
      int s0 = (l >> 4);
      bf16x8 a0 = *(const bf16x8*)(&As[buf][ra * 64 + ((s0 ^ (ra & 7)) * 8)]);
      bf16x8 a1 = *(const bf16x8*)(&As[buf][ra * 64 + (((s0 + 4) ^ (ra & 7)) * 8)]);
#pragma unroll
      for (int fn = 0; fn < 4; ++fn) {
        acc[fm][fn] = mfma16(a0, bfrag[fn][0], acc[fm][fn]);
        acc[fm][fn] = mfma16(a1, bfrag[fn][1], acc[fm][fn]);
      }
    }
  };

  stage(0, 0);
  stage(1, 1);
  for (int kt = 0; kt < NT; ++kt) {
    if (kt < NT - 1) {
      asm volatile("s_waitcnt vmcnt(8)" ::: "memory");
    } else {
      asm volatile("s_waitcnt vmcnt(0)" ::: "memory");
    }
    __builtin_amdgcn_s_barrier();
    __builtin_amdgcn_sched_barrier(0);
    compute(kt & 1);
    __builtin_amdgcn_s_barrier();
    if (kt + 2 < NT) stage(kt & 1, kt + 2);
  }

  int widx = n0 >> 10;
  int b = m0 >> 12;

#pragma unroll
  for (int fm = 0; fm < 8; ++fm) {
    int rowg = m0 + wr * 128 + fm * 16 + (l >> 4) * 4;
#pragma unroll
    for (int fn = 0; fn < 4; ++fn) {
      int col = (n0 & 1023) + wc * 64 + fn * 16 + (l & 15);
      if (widx == 2) {
        int chunk = (rowg & 4095) >> 7;
        int trow = rowg & 127;
        bf16x4 pk = { (bf16)acc[fm][fn][0], (bf16)acc[fm][fn][1],
                      (bf16)acc[fm][fn][2], (bf16)acc[fm][fn][3] };
        *(bf16x4*)(vT + ((long)(b * NC_ + chunk) * D_ + col) * T_ + trow) = pk;
      } else if (widx < 2) {
        bf16* dst = (widx == 0) ? qo : ko;
#pragma unroll
        for (int r = 0; r < 4; ++r)
          dst[(long)(rowg + r) * D_ + col] = (bf16)acc[fm][fn][r];
      } else {
        float bgv = bg[col];
#pragma unroll
        for (int r = 0; r < 4; ++r) {
          float x = acc[fm][fn][r] + bgv;
          go[(long)(rowg + r) * D_ + col] = (bf16)(1.0f / (1.0f + __expf(-x)));
        }
      }
    }
  }
}

// ---------------- QK^T: 128x256 (two j per block), BK=64, counted vmcnt ----------
// block = (pair-block pb, batch b). A = q_n [128xK]; B = k_j0|k_j1 [256xK].
__global__ __launch_bounds__(512, 1) void qk_kernel(
    const bf16* __restrict__ q, const bf16* __restrict__ k,
    bf16* __restrict__ Plo, bf16* __restrict__ Phi)
{
  __shared__ __align__(16) bf16 As[2][128 * 64];   // 32 KB
  __shared__ __align__(16) bf16 Bs[2][256 * 64];   // 64 KB
  const int K = 1024;
  const int NT = 16;
  int pb = blockIdx.x, b = blockIdx.y;
  // decode pb -> (n, jj): per-n block count = (n+2)>>1
  int n = 0, base = 0;
  while (base + ((n + 2) >> 1) <= pb) { base += (n + 2) >> 1; ++n; }
  int jj = pb - base;
  int j0 = jj * 2;
  int j1v = j0 + 1;                 // real second j (may exceed n)
  int j1 = (j1v <= n) ? j1v : j0;   // clamped for loads

  int t = threadIdx.x;
  int l = t & 63, w = t >> 6;
  int wr = (w >> 2) & 1, wc = w & 3;   // 2x4 waves; wave tile 64x64

  const bf16* Ab = q + (long)(b * S_ + n * T_) * K;
  const bf16* K0 = k + (long)(b * S_ + j0 * T_) * K;
  const bf16* K1 = k + (long)(b * S_ + j1 * T_) * K;

  int srow_off = t >> 3;
  int scol_swz = (((t & 7) ^ ((t >> 3) & 7)) * 8);
  int wdst = w << 9;

  f32x4 acc[4][4] = {};

  auto stage = [&](int buf, int kt) {
#pragma unroll
    for (int c = 0; c < 2; ++c) {
      int r = c * 64 + srow_off;
      gload16(Ab + (long)r * K + kt * 64 + scol_swz, &As[buf][c * 4096 + wdst]);
    }
#pragma unroll
    for (int c = 0; c < 4; ++c) {
      int r = (c & 1) * 64 + srow_off;
      const bf16* Ksrc = (c < 2) ? K0 : K1;
      gload16(Ksrc + (long)r * K + kt * 64 + scol_swz, &Bs[buf][c * 4096 + wdst]);
    }
  };

  auto compute = [&](int buf) {
    bf16x8 bfrag[4][2];
#pragma unroll
    for (int fn = 0; fn < 4; ++fn)
#pragma unroll
      for (int ks = 0; ks < 2; ++ks) {
        int rb = wc * 64 + fn * 16 + (l & 15);
        int sb = ks * 4 + (l >> 4);
        bfrag[fn][ks] = *(const bf16x8*)(&Bs[buf][rb * 64 + ((sb ^ (rb & 7)) * 8)]);
      }
#pragma unroll
    for (int fm = 0; fm < 4; ++fm) {
      int ra = wr * 64 + fm * 16 + (l & 15);
      int s0 = (l >> 4);
      bf16x8 a0 = *(const bf16x8*)(&As[buf][ra * 64 + ((s0 ^ (ra & 7)) * 8)]);
      bf16x8 a1 = *(const bf16x8*)(&As[buf][ra * 64 + (((s0 + 4) ^ (ra & 7)) * 8)]);
#pragma unroll
      for (int fn = 0; fn < 4; ++fn) {
        acc[fm][fn] = mfma16(a0, bfrag[fn][0], acc[fm][fn]);
        acc[fm][fn] = mfma16(a1, bfrag[fn][1], acc[fm][fn]);
      }
    }
  };

  stage(0, 0);
  stage(1, 1);
  for (int kt = 0; kt < NT; ++kt) {
    if (kt < NT - 1) {
      asm volatile("s_waitcnt vmcnt(6)" ::: "memory");
    } else {
      asm volatile("s_waitcnt vmcnt(0)" ::: "memory");
    }
    __builtin_amdgcn_s_barrier();
    __builtin_amdgcn_sched_barrier(0);
    compute(kt & 1);
    __builtin_amdgcn_s_barrier();
    if (kt + 2 < NT) stage(kt & 1, kt + 2);
  }

  const float upd = (1.0f - DECAY_) / (float)T_;
  // wc < 2 -> j0 half (cols 0..127); wc >= 2 -> j1 half. Wave-uniform select.
  int jsel = (wc < 2) ? j0 : j1v;
  bool valid = (wc < 2) || (j1v <= n);
  if (valid) {
    float c = powf(DECAY_, (float)(n - jsel)) * upd;
    int tile = b * NPAIR_ + n * (n + 1) / 2 + jsel;
    bf16* Pt = (tile < 1024) ? (Plo + (long)tile * 16384)
                             : (Phi + (long)(tile - 1024) * 16384);
#pragma unroll
    for (int fm = 0; fm < 4; ++fm) {
      int row = wr * 64 + fm * 16 + (l >> 4) * 4;
#pragma unroll
      for (int fn = 0; fn < 4; ++fn) {
        int colp = ((wc & 1) * 64) + fn * 16 + (l & 15);   // col within the 128-tile
#pragma unroll
        for (int r = 0; r < 4; ++r)
          Pt[(long)(row + r) * T_ + colp] = (bf16)(acc[fm][fn][r] * c);
      }
    }
  }
}

// ---------------- PV: 128x256 e-tiles, K=(n+1)*128 as 2(n+1) BK=64 steps ---------
// block = (et in [0,4), n desc, b). A = P_nj stream; B = vT rows e0..e0+255.
__global__ __launch_bounds__(512, 1) void pv_kernel(
    const bf16* __restrict__ Plo, const bf16* __restrict__ Phi,
    const bf16* __restrict__ vT, const bf16* __restrict__ g,
    bf16* __restrict__ mid)
{
  __shared__ __align__(16) bf16 As[2][128 * 64];   // 32 KB
  __shared__ __align__(16) bf16 Bs[2][256 * 64];   // 64 KB
  int et = blockIdx.x;
  int n  = 31 - blockIdx.y;
  int b  = blockIdx.z;
  int e0 = et * 256;
  int t = threadIdx.x;
  int l = t & 63, w = t >> 6;
  int wr = (w >> 2) & 1, wc = w & 3;

  int srow_off = t >> 3;
  int scol_swz = (((t & 7) ^ ((t >> 3) & 7)) * 8);
  int wdst = w << 9;
  int pbase = b * NPAIR_ + n * (n + 1) / 2;
  const bf16* Vbase = vT + (long)(b * NC_) * D_ * T_ + (long)e0 * T_;

  f32x4 acc[4][4] = {};

  auto stage = [&](int buf, int s) {
    int j = s >> 1, kt2 = s & 1;
    int tile = pbase + j;
    const bf16* Pt = (tile < 1024) ? (Plo + (long)tile * 16384)
                                   : (Phi + (long)(tile - 1024) * 16384);
    const bf16* Vt = Vbase + (long)j * D_ * T_;
#pragma unroll
    for (int c = 0; c < 2; ++c) {
      int r = c * 64 + srow_off;
      gload16(Pt + (long)r * T_ + kt2 * 64 + scol_swz, &As[buf][c * 4096 + wdst]);
    }
#pragma unroll
    for (int c = 0; c < 4; ++c) {
      int r = c * 64 + srow_off;
      gload16(Vt + (long)r * T_ + kt2 * 64 + scol_swz, &Bs[buf][c * 4096 + wdst]);
    }
  };

  auto compute = [&](int buf) {
    bf16x8 bfrag[4][2];
#pragma unroll
    for (int fn = 0; fn < 4; ++fn)
#pragma unroll
      for (int ks = 0; ks < 2; ++ks) {
        int rb = wc * 64 + fn * 16 + (l & 15);
        int sb = ks * 4 + (l >> 4);
        bfrag[fn][ks] = *(const bf16x8*)(&Bs[buf][rb * 64 + ((sb ^ (rb & 7)) * 8)]);
      }
#pragma unroll
    for (int fm = 0; fm < 4; ++fm) {
      int ra = wr * 64 + fm * 16 + (l & 15);
      int s0 = (l >> 4);
      bf16x8 a0 = *(const bf16x8*)(&As[buf][ra * 64 + ((s0 ^ (ra & 7)) * 8)]);
      bf16x8 a1 = *(const bf16x8*)(&As[buf][ra * 64 + (((s0 + 4) ^ (ra & 7)) * 8)]);
#pragma unroll
      for (int fn = 0; fn < 4; ++fn) {
        acc[fm][fn] = mfma16(a0, bfrag[fn][0], acc[fm][fn]);
        acc[fm][fn] = mfma16(a1, bfrag[fn][1], acc[fm][fn]);
      }
    }
  };

  int nsteps = 2 * (n + 1);
  stage(0, 0);
  stage(1, 1);
  for (int kt = 0; kt < nsteps; ++kt) {
    if (kt < nsteps - 1) {
      asm volatile("s_waitcnt vmcnt(6)" ::: "memory");
    } else {
      asm volatile("s_waitcnt vmcnt(0)" ::: "memory");
    }
    __builtin_amdgcn_s_barrier();
    __builtin_amdgcn_sched_barrier(0);
    compute(kt & 1);
    __builtin_amdgcn_s_barrier();
    if (kt + 2 < nsteps) stage(kt & 1, kt + 2);
  }

#pragma unroll
  for (int fm = 0; fm < 4; ++fm) {
    int trow = n * T_ + wr * 64 + fm * 16 + (l >> 4) * 4;
#pragma unroll
    for (int fn = 0; fn < 4; ++fn) {
      int col = e0 + wc * 64 + fn * 16 + (l & 15);
#pragma unroll
      for (int r = 0; r < 4; ++r) {
        long idx = ((long)b * S_ + trow + r) * D_ + col;
        float gv = (float)g[idx];
        mid[idx] = (bf16)(acc[fm][fn][r] * gv);
      }
    }
  }
}

// ---------------- output GEMM: 256x256, counted vmcnt, fp32 out ----------------
__global__ __launch_bounds__(512, 1) void gemm_out(
    const bf16* __restrict__ A, const bf16* __restrict__ W,
    float* __restrict__ C)
{
  __shared__ __align__(16) bf16 As[2][256 * 64];
  __shared__ __align__(16) bf16 Bs[2][256 * 64];
  const int K = 1024;
  const int NT = 16;
  int m0 = blockIdx.y * 256;
  int n0 = blockIdx.x * 256;
  int t = threadIdx.x;
  int l = t & 63, w = t >> 6;
  int wr = w >> 2, wc = w & 3;

  const bf16* Ab = A + (long)m0 * K;
  const bf16* Wb = W + (long)n0 * K;

  int srow_off = t >> 3;
  int scol_swz = (((t & 7) ^ ((t >> 3) & 7)) * 8);
  int wdst = w << 9;

  f32x4 acc[8][4] = {};

  auto stage = [&](int buf, int kt) {
#pragma unroll
    for (int c = 0; c < 4; ++c) {
      int r = c * 64 + srow_off;
      gload16(Ab + (long)r * K + kt * 64 + scol_swz, &As[buf][c * 4096 + wdst]);
      gload16(Wb + (long)r * K + kt * 64 + scol_swz, &Bs[buf][c * 4096 + wdst]);
    }
  };

  auto compute = [&](int buf) {
    bf16x8 bfrag[4][2];
#pragma unroll
    for (int fn = 0; fn < 4; ++fn)
#pragma unroll
      for (int ks = 0; ks < 2; ++ks) {
        int rb = wc * 64 + fn * 16 + (l & 15);
        int sb = ks * 4 + (l >> 4);
        bfrag[fn][ks] = *(const bf16x8*)(&Bs[buf][rb * 64 + ((sb ^ (rb & 7)) * 8)]);
      }
#pragma unroll
    for (int fm = 0; fm < 8; ++fm) {
      int ra = wr * 128 + fm * 16 + (l & 15);
      int s0 = (l >> 4);
      bf16x8 a0 = *(const bf16x8*)(&As[buf][ra * 64 + ((s0 ^ (ra & 7)) * 8)]);
      bf16x8 a1 = *(const bf16x8*)(&As[buf][ra * 64 + (((s0 + 4) ^ (ra & 7)) * 8)]);
#pragma unroll
      for (int fn = 0; fn < 4; ++fn) {
        acc[fm][fn] = mfma16(a0, bfrag[fn][0], acc[fm][fn]);
        acc[fm][fn] = mfma16(a1, bfrag[fn][1], acc[fm][fn]);
      }
    }
  };

  stage(0, 0);
  stage(1, 1);
  for (int kt = 0; kt < NT; ++kt) {
    if (kt < NT - 1) {
      asm volatile("s_waitcnt vmcnt(8)" ::: "memory");
    } else {
      asm volatile("s_waitcnt vmcnt(0)" ::: "memory");
    }
    __builtin_amdgcn_s_barrier();
    __builtin_amdgcn_sched_barrier(0);
    compute(kt & 1);
    __builtin_amdgcn_s_barrier();
    if (kt + 2 < NT) stage(kt & 1, kt + 2);
  }

#pragma unroll
  for (int fm = 0; fm < 8; ++fm) {
    int rowg = m0 + wr * 128 + fm * 16 + (l >> 4) * 4;
#pragma unroll
    for (int fn = 0; fn < 4; ++fn) {
      int col = n0 + wc * 64 + fn * 16 + (l & 15);
#pragma unroll
      for (int r = 0; r < 4; ++r)
        C[(long)(rowg + r) * D_ + col] = acc[fm][fn][r];
    }
  }
}

// ---------------- launcher ----------------
extern "C" void kernel_launch(void* const* d_in, const int* in_sizes, int n_in,
                              void* d_out, int out_size, void* d_ws, size_t ws_size,
                              hipStream_t stream) {
  const float* h  = (const float*)d_in[0];
  const float* Wq = (const float*)d_in[2];
  const float* Wk = (const float*)d_in[3];
  const float* Wv = (const float*)d_in[4];
  const float* Wo = (const float*)d_in[5];
  const float* Wg = (const float*)d_in[6];
  const float* bg = (const float*)d_in[7];
  float* out = (float*)d_out;

  bf16* ws = (bf16*)d_ws;
  const long NHD = (long)B_ * S_ * D_;   // 16,777,216 (= exactly 1024 P tiles)
  const long NW  = (long)D_ * D_;

  bf16* h_bf  = ws;  ws += NHD;          // dead after proj -> reused as P_lo
  bf16* Wcat  = ws;  ws += 4 * NW;
  bf16* Wo_bf = ws;  ws += NW;
  bf16* q_bf  = ws;  ws += NHD;          // dead after qk -> reused as mid
  bf16* k_bf  = ws;  ws += NHD;
  bf16* vT    = ws;  ws += NHD;
  bf16* g_bf  = ws;  ws += NHD;
  bf16* P_hi  = ws;  ws += (long)(4 * NPAIR_ - 1024) * 16384;  // 1088 tiles

  bf16* P_lo = h_bf;
  bf16* mid  = q_bf;

  cast_kernel<<<4096, 256, 0, stream>>>(h, h_bf, (int)NHD);
  wcast_kernel<<<5120, 256, 0, stream>>>(Wq, Wk, Wv, Wg, Wo, Wcat, Wo_bf);

  gemm_proj<<<dim3(16, 64), 512, 0, stream>>>(h_bf, Wcat, bg, q_bf, k_bf, vT, g_bf);
  qk_kernel<<<dim3(272, 4), 512, 0, stream>>>(q_bf, k_bf, P_lo, P_hi);
  pv_kernel<<<dim3(4, 32, 4), 512, 0, stream>>>(P_lo, P_hi, vT, g_bf, mid);
  gemm_out<<<dim3(4, 64), 512, 0, stream>>>(mid, Wo_bf, out);
}